// Round 1
// baseline (616.488 us; speedup 1.0000x reference)
//
#include <hip/hip_runtime.h>
#include <hip/hip_bf16.h>

// Problem constants
#define S_TOK 2048
#define DFF 11008
#define DMODEL 4096
#define TOPK 4403      // int(0.4 * 11008)
#define KPAD 4416      // TOPK padded up to multiple of 64
#define RSPLIT 16
#define RCHUNK 128     // 2048 / 16

typedef unsigned short u16;
typedef __attribute__((ext_vector_type(8))) short short8;   // 8 x bf16 (4 VGPRs)
typedef __attribute__((ext_vector_type(4))) float floatx4;  // MFMA accumulator

// ---------------------------------------------------------------------------
// 1) scores[j] = sum_s relu(x[s][j]); fp64 accumulation in a FIXED split-16
//    tree so the result is deterministic and near-exact (selection must match
//    numpy's top-K set).
// ---------------------------------------------------------------------------
__global__ __launch_bounds__(256) void score_partial_k(const float* __restrict__ x,
                                                       double* __restrict__ partials) {
  int c = blockIdx.x * 256 + threadIdx.x;      // 43 * 256 == 11008 exact
  int r0 = blockIdx.y * RCHUNK;
  const float* p = x + (size_t)r0 * DFF + c;
  double acc = 0.0;
#pragma unroll 8
  for (int r = 0; r < RCHUNK; ++r) {
    float v = p[(size_t)r * DFF];
    acc += (v > 0.f) ? (double)v : 0.0;
  }
  partials[(size_t)blockIdx.y * DFF + c] = acc;
}

__global__ __launch_bounds__(256) void score_reduce_k(const double* __restrict__ partials,
                                                      double* __restrict__ scores) {
  int c = blockIdx.x * 256 + threadIdx.x;
  double s = 0.0;
#pragma unroll
  for (int b = 0; b < RSPLIT; ++b) s += partials[(size_t)b * DFF + c];
  scores[c] = s;
}

// ---------------------------------------------------------------------------
// 2) top-K select: radix-select (8-bit digits, MSB first) on the uint64 bit
//    pattern of the fp64 score (monotone for non-negative doubles), then an
//    index-ordered compaction with lowest-index tie-break (matches lax.top_k).
//    Output idx[0..TOPK) sorted ascending; idx[TOPK..KPAD) = -1.
// ---------------------------------------------------------------------------
#define TCH 11  // 11 * 1024 = 11264 >= 11008

__global__ __launch_bounds__(1024) void topk_k(const double* __restrict__ scores,
                                               int* __restrict__ idx) {
  __shared__ int hist[256];
  __shared__ int scanbuf[1024];
  __shared__ unsigned long long sh_prefix;
  __shared__ int sh_need;
  const int tid = threadIdx.x;
  const int j0 = tid * TCH;

  unsigned long long key[TCH];
#pragma unroll
  for (int i = 0; i < TCH; ++i) {
    int j = j0 + i;
    key[i] = (j < DFF) ? (unsigned long long)__double_as_longlong(scores[j]) : 0ull;
  }

  unsigned long long prefix = 0;
  int remaining = TOPK;
  for (int d = 7; d >= 0; --d) {
    if (tid < 256) hist[tid] = 0;
    __syncthreads();
#pragma unroll
    for (int i = 0; i < TCH; ++i) {
      if (j0 + i >= DFF) break;
      unsigned long long k = key[i];
      bool match = (d == 7) ? true : ((k >> ((d + 1) * 8)) == (prefix >> ((d + 1) * 8)));
      if (match) atomicAdd(&hist[(int)((k >> (d * 8)) & 255ull)], 1);
    }
    __syncthreads();
    if (tid == 0) {
      int c = 0, chosen = 0, newrem = remaining;
      for (int g = 255; g >= 0; --g) {
        c += hist[g];
        if (c >= remaining) { chosen = g; newrem = remaining - (c - hist[g]); break; }
      }
      sh_prefix = prefix | ((unsigned long long)chosen << (d * 8));
      sh_need = newrem;
    }
    __syncthreads();
    prefix = sh_prefix;
    remaining = sh_need;
  }
  const unsigned long long T = prefix;   // K-th largest key
  const int needEq = remaining;          // how many ==T to take (lowest index first)

  // rank the ==T elements by index
  int cntEq = 0;
#pragma unroll
  for (int i = 0; i < TCH; ++i)
    if (j0 + i < DFF && key[i] == T) cntEq++;
  scanbuf[tid] = cntEq;
  __syncthreads();
  for (int off = 1; off < 1024; off <<= 1) {
    int v = (tid >= off) ? scanbuf[tid - off] : 0;
    __syncthreads();
    scanbuf[tid] += v;
    __syncthreads();
  }
  int eqBefore = scanbuf[tid] - cntEq;
  __syncthreads();

  // select + index-ordered compaction
  bool sel[TCH];
  int cntSel = 0, eqRank = eqBefore;
#pragma unroll
  for (int i = 0; i < TCH; ++i) {
    bool s = false;
    if (j0 + i < DFF) {
      if (key[i] > T) s = true;
      else if (key[i] == T) { s = (eqRank < needEq); eqRank++; }
    }
    sel[i] = s;
    cntSel += s ? 1 : 0;
  }
  scanbuf[tid] = cntSel;
  __syncthreads();
  for (int off = 1; off < 1024; off <<= 1) {
    int v = (tid >= off) ? scanbuf[tid - off] : 0;
    __syncthreads();
    scanbuf[tid] += v;
    __syncthreads();
  }
  int pos = scanbuf[tid] - cntSel;
#pragma unroll
  for (int i = 0; i < TCH; ++i)
    if (sel[i]) idx[pos++] = j0 + i;
  __syncthreads();
  if (tid < KPAD - TOPK) idx[TOPK + tid] = -1;  // zero-pad slots for the GEMM
}

// ---------------------------------------------------------------------------
// 3) gather + cast to bf16 (RNE): dst[r][k] = bf16(src[r][idx[k]]), 0 for pad.
//    idx is sorted ascending -> gathered reads are monotone (good L1/L2 reuse).
// ---------------------------------------------------------------------------
__device__ __forceinline__ u16 f2bf_rne(float f) {
  unsigned u = __float_as_uint(f);
  unsigned r = (u + 0x7fffu + ((u >> 16) & 1u)) >> 16;
  return (u16)r;
}

__global__ __launch_bounds__(256) void gather_bf16_k(const float* __restrict__ src,
                                                     const int* __restrict__ idx,
                                                     u16* __restrict__ dst) {
  int kg = blockIdx.x * 256 + threadIdx.x;   // group of 8 outputs
  if (kg >= KPAD / 8) return;
  int r = blockIdx.y;
  int k0 = kg * 8;
  const float* srow = src + (size_t)r * DFF;
  u16 o[8];
#pragma unroll
  for (int i = 0; i < 8; ++i) {
    int id = idx[k0 + i];
    float v = (id >= 0) ? srow[id] : 0.f;
    o[i] = f2bf_rne(v);
  }
  uint4 pack;
  pack.x = (unsigned)o[0] | ((unsigned)o[1] << 16);
  pack.y = (unsigned)o[2] | ((unsigned)o[3] << 16);
  pack.z = (unsigned)o[4] | ((unsigned)o[5] << 16);
  pack.w = (unsigned)o[6] | ((unsigned)o[7] << 16);
  *(uint4*)(dst + (size_t)r * KPAD + k0) = pack;
}

// ---------------------------------------------------------------------------
// 4) NT GEMM: C[M,N] f32 = A[M,K] bf16 · B[N,K] bf16^T   (both K-contiguous)
//    m97 structure: 128x128x64 tiles, global_load_lds width 16, 16x16x32 MFMA,
//    4 waves in 2x2, each wave 64x64 (4x4 MFMA tiles).
// ---------------------------------------------------------------------------
#define BM 128
#define BN 128
#define BK 64

__device__ __forceinline__ void async_load16(const void* g, void* l) {
  __builtin_amdgcn_global_load_lds(
      (const __attribute__((address_space(1))) void*)g,
      (__attribute__((address_space(3))) void*)l, 16, 0, 0);
}

__global__ __launch_bounds__(256) void gemm_bt_k(const u16* __restrict__ A,
                                                 const u16* __restrict__ B,
                                                 float* __restrict__ C,
                                                 int M, int N, int Kt) {
  __shared__ __align__(16) u16 As[BM * BK];
  __shared__ __align__(16) u16 Bs[BN * BK];
  const int tid = threadIdx.x;
  const int lane = tid & 63;
  const int wave = tid >> 6;
  const int bm = blockIdx.y * BM;
  const int bn = blockIdx.x * BN;
  const int wrow = (wave >> 1) * 64;
  const int wcol = (wave & 1) * 64;

  floatx4 acc[4][4];
#pragma unroll
  for (int i = 0; i < 4; ++i)
#pragma unroll
    for (int j = 0; j < 4; ++j)
      acc[i][j] = (floatx4){0.f, 0.f, 0.f, 0.f};

  // staging: per issue, one wave covers 8 rows x 64 cols (lane -> base + lane*16B)
  const int srow = wave * 8 + (lane >> 3);
  const int scol = (lane & 7) * 8;
  const u16* gA = A + (size_t)(bm + srow) * Kt + scol;
  const u16* gB = B + (size_t)(bn + srow) * Kt + scol;
  u16* lA = As + wave * 8 * BK;  // wave-uniform LDS base
  u16* lB = Bs + wave * 8 * BK;

  const u16* aptr = As + (wrow + (lane & 15)) * BK + (lane >> 4) * 8;
  const u16* bptr = Bs + (wcol + (lane & 15)) * BK + (lane >> 4) * 8;

  for (int k0 = 0; k0 < Kt; k0 += BK) {
#pragma unroll
    for (int i = 0; i < 4; ++i) {
      async_load16(gA + k0 + (size_t)i * 32 * Kt, lA + i * 32 * BK);
      async_load16(gB + k0 + (size_t)i * 32 * Kt, lB + i * 32 * BK);
    }
    __syncthreads();  // compiler drains vmcnt before s_barrier
#pragma unroll
    for (int ks = 0; ks < BK; ks += 32) {
      short8 af[4], bf[4];
#pragma unroll
      for (int i = 0; i < 4; ++i) af[i] = *(const short8*)(aptr + i * 16 * BK + ks);
#pragma unroll
      for (int j = 0; j < 4; ++j) bf[j] = *(const short8*)(bptr + j * 16 * BK + ks);
#pragma unroll
      for (int i = 0; i < 4; ++i)
#pragma unroll
        for (int j = 0; j < 4; ++j)
          acc[i][j] = __builtin_amdgcn_mfma_f32_16x16x32_bf16(af[i], bf[j], acc[i][j], 0, 0, 0);
    }
    __syncthreads();
  }

  // C/D layout (verified m89/m91): col = lane&15, row = (lane>>4)*4 + reg
#pragma unroll
  for (int i = 0; i < 4; ++i) {
#pragma unroll
    for (int j = 0; j < 4; ++j) {
      int row = bm + wrow + i * 16 + (lane >> 4) * 4;
      int col = bn + wcol + j * 16 + (lane & 15);
      float* p = C + (size_t)row * N + col;
#pragma unroll
      for (int r = 0; r < 4; ++r) p[(size_t)r * N] = acc[i][j][r];
    }
  }
}

// ---------------------------------------------------------------------------
// launch
// ---------------------------------------------------------------------------
extern "C" void kernel_launch(void* const* d_in, const int* in_sizes, int n_in,
                              void* d_out, int out_size, void* d_ws, size_t ws_size,
                              hipStream_t stream) {
  const float* x = (const float*)d_in[0];  // [2048, 11008]
  const float* W = (const float*)d_in[1];  // [4096, 11008]
  float* out = (float*)d_out;              // [2048, 4096]
  char* ws = (char*)d_ws;

  // workspace layout (total ~54 MB)
  double* partials = (double*)ws;                                        // 16*11008*8 = 1,409,024 B
  double* scores = (double*)(ws + 1409024);                              // 11008*8   =    88,064 B
  int* idx = (int*)(ws + 1409024 + 88064);                               // 4416*4    =    17,664 B
  u16* Xg = (u16*)(ws + (size_t)2 * 1024 * 1024);                        // 2048*4416*2 = 18,087,936 B
  u16* Wg = (u16*)(ws + (size_t)2 * 1024 * 1024 + (size_t)S_TOK * KPAD * 2);  // 4096*4416*2

  score_partial_k<<<dim3(DFF / 256, RSPLIT), 256, 0, stream>>>(x, partials);
  score_reduce_k<<<dim3(DFF / 256), 256, 0, stream>>>(partials, scores);
  topk_k<<<1, 1024, 0, stream>>>(scores, idx);
  gather_bf16_k<<<dim3(3, S_TOK), 256, 0, stream>>>(x, idx, Xg);
  gather_bf16_k<<<dim3(3, DMODEL), 256, 0, stream>>>(W, idx, Wg);
  gemm_bt_k<<<dim3(DMODEL / BN, S_TOK / BM), 256, 0, stream>>>(Xg, Wg, out, S_TOK, DMODEL, KPAD);
}

// Round 2
// 552.015 us; speedup vs baseline: 1.1168x; 1.1168x over previous
//
#include <hip/hip_runtime.h>
#include <hip/hip_bf16.h>

// Problem constants
#define S_TOK 2048
#define DFF 11008
#define DMODEL 4096
#define TOPK 4403      // int(0.4 * 11008)
#define KPAD 4416      // TOPK padded up to multiple of 64
#define RSPLIT 16
#define RCHUNK 128     // 2048 / 16

typedef unsigned short u16;
typedef unsigned long long u64;
typedef __attribute__((ext_vector_type(8))) short short8;   // 8 x bf16 (4 VGPRs)
typedef __attribute__((ext_vector_type(4))) float floatx4;  // MFMA accumulator

// ---------------------------------------------------------------------------
// 1) scores[j] = sum_s relu(x[s][j]); fp64 accumulation in a FIXED split-16
//    tree -> deterministic, near-exact (selection must match numpy's top-K).
// ---------------------------------------------------------------------------
__global__ __launch_bounds__(256) void score_partial_k(const float* __restrict__ x,
                                                       double* __restrict__ partials) {
  int c = blockIdx.x * 256 + threadIdx.x;      // 43 * 256 == 11008 exact
  int r0 = blockIdx.y * RCHUNK;
  const float* p = x + (size_t)r0 * DFF + c;
  double acc = 0.0;
#pragma unroll 8
  for (int r = 0; r < RCHUNK; ++r) {
    float v = p[(size_t)r * DFF];
    acc += (v > 0.f) ? (double)v : 0.0;
  }
  partials[(size_t)blockIdx.y * DFF + c] = acc;
}

__global__ __launch_bounds__(256) void score_reduce_k(const double* __restrict__ partials,
                                                      double* __restrict__ scores) {
  int c = blockIdx.x * 256 + threadIdx.x;
  double s = 0.0;
#pragma unroll
  for (int b = 0; b < RSPLIT; ++b) s += partials[(size_t)b * DFF + c];
  scores[c] = s;
}

// ---------------------------------------------------------------------------
// 2) top-K select (radix-select on fp64 bit pattern, MSB-first 8-bit digits,
//    lowest-index tie-break == lax.top_k). Emits rank[j] = #selected cols < j
//    (exclusive scan of the selection mask), rank[DFF] = TOPK. Selected col j
//    lands at compact position rank[j] -> ascending-index order (set-equal to
//    the reference selection; einsum over the set is order-independent).
//    Per-wave histograms cut LDS-atomic contention 16x.
// ---------------------------------------------------------------------------
#define TCH 11   // 11 * 1024 = 11264 >= 11008
#define NWAVE 16

__global__ __launch_bounds__(1024) void topk_k(const double* __restrict__ scores,
                                               int* __restrict__ rank) {
  __shared__ int histw[NWAVE * 256];  // 16 KB per-wave histograms
  __shared__ int hist[256];
  __shared__ int scanbuf[1024];
  __shared__ u64 sh_prefix;
  __shared__ int sh_need;
  const int tid = threadIdx.x;
  const int wave = tid >> 6;
  const int j0 = tid * TCH;

  u64 key[TCH];
#pragma unroll
  for (int i = 0; i < TCH; ++i) {
    int j = j0 + i;
    key[i] = (j < DFF) ? (u64)__double_as_longlong(scores[j]) : 0ull;
  }

  u64 prefix = 0;
  int remaining = TOPK;
  for (int d = 7; d >= 0; --d) {
#pragma unroll
    for (int i = tid; i < NWAVE * 256; i += 1024) histw[i] = 0;
    __syncthreads();
#pragma unroll
    for (int i = 0; i < TCH; ++i) {
      if (j0 + i >= DFF) break;
      u64 k = key[i];
      bool match = (d == 7) ? true : ((k >> ((d + 1) * 8)) == (prefix >> ((d + 1) * 8)));
      if (match) atomicAdd(&histw[wave * 256 + (int)((k >> (d * 8)) & 255ull)], 1);
    }
    __syncthreads();
    if (tid < 256) {
      int s = 0;
#pragma unroll
      for (int w = 0; w < NWAVE; ++w) s += histw[w * 256 + tid];
      hist[tid] = s;
    }
    __syncthreads();
    if (tid == 0) {
      int c = 0, chosen = 0, newrem = remaining;
      for (int g = 255; g >= 0; --g) {
        c += hist[g];
        if (c >= remaining) { chosen = g; newrem = remaining - (c - hist[g]); break; }
      }
      sh_prefix = prefix | ((u64)chosen << (d * 8));
      sh_need = newrem;
    }
    __syncthreads();
    prefix = sh_prefix;
    remaining = sh_need;
    __syncthreads();
  }
  const u64 T = prefix;         // K-th largest key
  const int needEq = remaining; // how many ==T to take (lowest index first)

  // rank the ==T elements by index
  int cntEq = 0;
#pragma unroll
  for (int i = 0; i < TCH; ++i)
    if (j0 + i < DFF && key[i] == T) cntEq++;
  scanbuf[tid] = cntEq;
  __syncthreads();
  for (int off = 1; off < 1024; off <<= 1) {
    int v = (tid >= off) ? scanbuf[tid - off] : 0;
    __syncthreads();
    scanbuf[tid] += v;
    __syncthreads();
  }
  int eqBefore = scanbuf[tid] - cntEq;
  __syncthreads();

  // selection + global positions
  bool sel[TCH];
  int cntSel = 0, eqRank = eqBefore;
#pragma unroll
  for (int i = 0; i < TCH; ++i) {
    bool s = false;
    if (j0 + i < DFF) {
      if (key[i] > T) s = true;
      else if (key[i] == T) { s = (eqRank < needEq); eqRank++; }
    }
    sel[i] = s;
    cntSel += s ? 1 : 0;
  }
  scanbuf[tid] = cntSel;
  __syncthreads();
  for (int off = 1; off < 1024; off <<= 1) {
    int v = (tid >= off) ? scanbuf[tid - off] : 0;
    __syncthreads();
    scanbuf[tid] += v;
    __syncthreads();
  }
  int running = scanbuf[tid] - cntSel;
#pragma unroll
  for (int i = 0; i < TCH; ++i) {
    int j = j0 + i;
    if (j < DFF) {
      rank[j] = running;
      if (sel[i]) running++;
    }
  }
  if (tid == 0) rank[DFF] = TOPK;
}

// ---------------------------------------------------------------------------
// 3) compaction gather: coalesced float4 reads of a contiguous source slab,
//    LDS compaction at rank[c]-rank[c0], then one dense contiguous store of
//    the block's destination window. Reads = ideal coalesced; writes dense.
//    GNR rows per block amortize the rank[] loads.
// ---------------------------------------------------------------------------
__device__ __forceinline__ u16 f2bf_rne(float f) {
  unsigned u = __float_as_uint(f);
  unsigned r = (u + 0x7fffu + ((u >> 16) & 1u)) >> 16;
  return (u16)r;
}

#define GCW 1024
#define GNR 4

__global__ __launch_bounds__(256) void compact_gather_k(const float* __restrict__ src,
                                                        const int* __restrict__ rank,
                                                        u16* __restrict__ dst) {
  __shared__ u16 buf[GNR][GCW];
  __shared__ int sh_se[2];
  const int c0 = blockIdx.x * GCW;
  const int row0 = blockIdx.y * GNR;
  if (threadIdx.x == 0) {
    int cend = c0 + GCW; if (cend > DFF) cend = DFF;
    sh_se[0] = rank[c0];
    sh_se[1] = rank[cend];
  }
  __syncthreads();
  const int start = sh_se[0];
  const int total = sh_se[1] - start;
  if (total <= 0) return;

  const int c = c0 + threadIdx.x * 4;
  int r0 = 0, r1 = 0, r2 = 0, r3 = 0, r4 = 0;
  if (c < DFF) {
    r0 = rank[c]; r1 = rank[c + 1]; r2 = rank[c + 2]; r3 = rank[c + 3]; r4 = rank[c + 4];
  }
#pragma unroll
  for (int rr = 0; rr < GNR; ++rr) {
    if (c < DFF) {
      float4 v = *(const float4*)(src + (size_t)(row0 + rr) * DFF + c);
      if (r1 > r0) buf[rr][r0 - start] = f2bf_rne(v.x);
      if (r2 > r1) buf[rr][r1 - start] = f2bf_rne(v.y);
      if (r3 > r2) buf[rr][r2 - start] = f2bf_rne(v.z);
      if (r4 > r3) buf[rr][r3 - start] = f2bf_rne(v.w);
    }
  }
  __syncthreads();
#pragma unroll
  for (int rr = 0; rr < GNR; ++rr) {
    u16* d = dst + (size_t)(row0 + rr) * KPAD + start;
    for (int t = threadIdx.x; t < total; t += 256) d[t] = buf[rr][t];
  }
}

// zero the KPAD-TOPK pad columns (ws is poisoned 0xAA before every launch)
__global__ __launch_bounds__(256) void padzero_k(u16* __restrict__ dst, int R) {
  const int npad = KPAD - TOPK;  // 13
  int i = blockIdx.x * 256 + threadIdx.x;
  if (i < R * npad) {
    int r = i / npad, k = i - r * npad;
    dst[(size_t)r * KPAD + TOPK + k] = 0;
  }
}

// ---------------------------------------------------------------------------
// 4) NT GEMM: C[M,N] f32 = A[M,K] bf16 · B[N,K] bf16^T   (both K-contiguous)
//    m97 structure: 128x128x64 tiles, global_load_lds width 16, 16x16x32 MFMA.
// ---------------------------------------------------------------------------
#define BM 128
#define BN 128
#define BK 64

__device__ __forceinline__ void async_load16(const void* g, void* l) {
  __builtin_amdgcn_global_load_lds(
      (const __attribute__((address_space(1))) void*)g,
      (__attribute__((address_space(3))) void*)l, 16, 0, 0);
}

__global__ __launch_bounds__(256) void gemm_bt_k(const u16* __restrict__ A,
                                                 const u16* __restrict__ B,
                                                 float* __restrict__ C,
                                                 int M, int N, int Kt) {
  __shared__ __align__(16) u16 As[BM * BK];
  __shared__ __align__(16) u16 Bs[BN * BK];
  const int tid = threadIdx.x;
  const int lane = tid & 63;
  const int wave = tid >> 6;
  const int bm = blockIdx.y * BM;
  const int bn = blockIdx.x * BN;
  const int wrow = (wave >> 1) * 64;
  const int wcol = (wave & 1) * 64;

  floatx4 acc[4][4];
#pragma unroll
  for (int i = 0; i < 4; ++i)
#pragma unroll
    for (int j = 0; j < 4; ++j)
      acc[i][j] = (floatx4){0.f, 0.f, 0.f, 0.f};

  const int srow = wave * 8 + (lane >> 3);
  const int scol = (lane & 7) * 8;
  const u16* gA = A + (size_t)(bm + srow) * Kt + scol;
  const u16* gB = B + (size_t)(bn + srow) * Kt + scol;
  u16* lA = As + wave * 8 * BK;  // wave-uniform LDS base
  u16* lB = Bs + wave * 8 * BK;

  const u16* aptr = As + (wrow + (lane & 15)) * BK + (lane >> 4) * 8;
  const u16* bptr = Bs + (wcol + (lane & 15)) * BK + (lane >> 4) * 8;

  for (int k0 = 0; k0 < Kt; k0 += BK) {
#pragma unroll
    for (int i = 0; i < 4; ++i) {
      async_load16(gA + k0 + (size_t)i * 32 * Kt, lA + i * 32 * BK);
      async_load16(gB + k0 + (size_t)i * 32 * Kt, lB + i * 32 * BK);
    }
    __syncthreads();
#pragma unroll
    for (int ks = 0; ks < BK; ks += 32) {
      short8 af[4], bf[4];
#pragma unroll
      for (int i = 0; i < 4; ++i) af[i] = *(const short8*)(aptr + i * 16 * BK + ks);
#pragma unroll
      for (int j = 0; j < 4; ++j) bf[j] = *(const short8*)(bptr + j * 16 * BK + ks);
#pragma unroll
      for (int i = 0; i < 4; ++i)
#pragma unroll
        for (int j = 0; j < 4; ++j)
          acc[i][j] = __builtin_amdgcn_mfma_f32_16x16x32_bf16(af[i], bf[j], acc[i][j], 0, 0, 0);
    }
    __syncthreads();
  }

  // C/D layout (verified m89/m91): col = lane&15, row = (lane>>4)*4 + reg
#pragma unroll
  for (int i = 0; i < 4; ++i) {
#pragma unroll
    for (int j = 0; j < 4; ++j) {
      int row = bm + wrow + i * 16 + (lane >> 4) * 4;
      int col = bn + wcol + j * 16 + (lane & 15);
      float* p = C + (size_t)row * N + col;
#pragma unroll
      for (int r = 0; r < 4; ++r) p[(size_t)r * N] = acc[i][j][r];
    }
  }
}

// ---------------------------------------------------------------------------
// launch
// ---------------------------------------------------------------------------
extern "C" void kernel_launch(void* const* d_in, const int* in_sizes, int n_in,
                              void* d_out, int out_size, void* d_ws, size_t ws_size,
                              hipStream_t stream) {
  const float* x = (const float*)d_in[0];  // [2048, 11008]
  const float* W = (const float*)d_in[1];  // [4096, 11008]
  float* out = (float*)d_out;              // [2048, 4096]
  char* ws = (char*)d_ws;

  // workspace layout (~54 MB)
  double* partials = (double*)ws;                      // 16*11008*8 = 1,409,024 B
  double* scores = (double*)(ws + 1409024);            // 11008*8    =    88,064 B
  int* rank = (int*)(ws + 1409024 + 88064);            // (11008+1)*4 =  44,036 B
  u16* Xg = (u16*)(ws + (size_t)2 * 1024 * 1024);      // 2048*4416*2 = 18,087,936 B
  u16* Wg = (u16*)(ws + (size_t)2 * 1024 * 1024 + (size_t)S_TOK * KPAD * 2);  // 4096*4416*2

  score_partial_k<<<dim3(DFF / 256, RSPLIT), 256, 0, stream>>>(x, partials);
  score_reduce_k<<<dim3(DFF / 256), 256, 0, stream>>>(partials, scores);
  topk_k<<<1, 1024, 0, stream>>>(scores, rank);
  padzero_k<<<dim3((S_TOK * (KPAD - TOPK) + 255) / 256), 256, 0, stream>>>(Xg, S_TOK);
  padzero_k<<<dim3((DMODEL * (KPAD - TOPK) + 255) / 256), 256, 0, stream>>>(Wg, DMODEL);
  compact_gather_k<<<dim3((DFF + GCW - 1) / GCW, S_TOK / GNR), 256, 0, stream>>>(x, rank, Xg);
  compact_gather_k<<<dim3((DFF + GCW - 1) / GCW, DMODEL / GNR), 256, 0, stream>>>(W, rank, Wg);
  gemm_bt_k<<<dim3(DMODEL / BN, S_TOK / BM), 256, 0, stream>>>(Xg, Wg, out, S_TOK, DMODEL, KPAD);
}

// Round 3
// 498.030 us; speedup vs baseline: 1.2379x; 1.1084x over previous
//
#include <hip/hip_runtime.h>
#include <hip/hip_bf16.h>

// Problem constants
#define S_TOK 2048
#define DFF 11008
#define DMODEL 4096
#define TOPK 4403      // int(0.4 * 11008)
#define KPAD 4416      // TOPK padded up to multiple of 64
#define RSPLIT 16
#define RCHUNK 128     // 2048 / 16
#define TCH 11         // 11 * 1024 = 11264 >= 11008

typedef unsigned short u16;
typedef unsigned int u32;
typedef unsigned long long u64;
typedef __attribute__((ext_vector_type(8))) short short8;   // 8 x bf16 (4 VGPRs)
typedef __attribute__((ext_vector_type(4))) float floatx4;  // MFMA accumulator

// ---------------------------------------------------------------------------
// 1) partial scores: fp64 accumulation in a FIXED split-16 tree (deterministic,
//    near-exact; identical numeric path to the passing rounds 1-2).
// ---------------------------------------------------------------------------
__global__ __launch_bounds__(256) void score_partial_k(const float* __restrict__ x,
                                                       double* __restrict__ partials) {
  int c = blockIdx.x * 256 + threadIdx.x;      // 43 * 256 == 11008 exact
  int r0 = blockIdx.y * RCHUNK;
  const float* p = x + (size_t)r0 * DFF + c;
  double acc = 0.0;
#pragma unroll 8
  for (int r = 0; r < RCHUNK; ++r) {
    float v = p[(size_t)r * DFF];
    acc += (v > 0.f) ? (double)v : 0.0;
  }
  partials[(size_t)blockIdx.y * DFF + c] = acc;
}

// ---------------------------------------------------------------------------
// 2) fused reduce + top-K select, latency-optimized single block.
//    - coalesced reduce of the 16 partials (same b=0..15 fp64 chain as before
//      -> bit-identical scores -> same selection as the passing rounds)
//    - radix-select on 32-bit keys (top 32 bits of fp64 pattern): 4 passes
//    - parallel suffix-sum bucket pick (no serial tid-0 loop)
//    - exact tie-break of key32-equal columns on full fp64 key, lowest index
//      first (== lax.top_k order), via small LDS group list
//    - wave-shuffle block scan for rank[] (2 barriers, not 40)
//    rank[j] = #selected < j; rank[DFF] = TOPK.
// ---------------------------------------------------------------------------
#define HG 8  // histogram groups (2 waves share one)

__device__ __forceinline__ int block_incl_scan(int v, int tid, int* wsums) {
  int lane = tid & 63, wave = tid >> 6;
#pragma unroll
  for (int off = 1; off < 64; off <<= 1) {
    int n = __shfl_up(v, off, 64);
    if (lane >= off) v += n;
  }
  if (lane == 63) wsums[wave] = v;
  __syncthreads();
  if (wave == 0) {
    int w = (lane < 16) ? wsums[lane] : 0;
#pragma unroll
    for (int off = 1; off < 16; off <<= 1) {
      int n = __shfl_up(w, off, 64);
      if (lane >= off) w += n;
    }
    if (lane < 16) wsums[lane] = w;  // inclusive wave totals
  }
  __syncthreads();
  int base = (wave > 0) ? wsums[wave - 1] : 0;
  return base + v;
}

__global__ __launch_bounds__(1024) void topk32_k(const double* __restrict__ partials,
                                                 double* __restrict__ scores,
                                                 int* __restrict__ rank) {
  __shared__ u32 keysh[DFF];        // 44,032 B
  __shared__ int histw[HG * 256];   //  8,192 B
  __shared__ int sbuf[256];
  __shared__ int wsums[16];
  __shared__ u32 sh_prefix;
  __shared__ int sh_need;
  __shared__ int gcount;
  __shared__ int gidx[256];
  __shared__ u64 gkey[256];
  const int tid = threadIdx.x;
  const int wave = tid >> 6;

  // Phase A: coalesced reduce; scores -> global, key32 -> LDS
#pragma unroll
  for (int s = 0; s < 11; ++s) {
    int j = tid + s * 1024;
    if (j < DFF) {
      double acc = 0.0;
#pragma unroll
      for (int b = 0; b < RSPLIT; ++b) acc += partials[(size_t)b * DFF + j];
      scores[j] = acc;
      keysh[j] = (u32)(((u64)__double_as_longlong(acc)) >> 32);
    }
  }
  if (tid == 0) gcount = 0;
  __syncthreads();

  // thread-local keys: 11 consecutive columns
  const int j0 = tid * TCH;
  u32 key[TCH];
#pragma unroll
  for (int i = 0; i < TCH; ++i) {
    int j = j0 + i;
    key[i] = (j < DFF) ? keysh[j] : 0u;
  }

  // 4-pass radix select (MSB-first 8-bit digits)
  u32 prefix = 0;
  int remaining = TOPK;
  for (int d = 3; d >= 0; --d) {
    for (int i = tid; i < HG * 256; i += 1024) histw[i] = 0;
    __syncthreads();
    const int hb = (wave >> 1) * 256;
#pragma unroll
    for (int i = 0; i < TCH; ++i) {
      if (j0 + i >= DFF) break;
      u32 k = key[i];
      bool match = (d == 3) || ((k >> ((d + 1) * 8)) == (prefix >> ((d + 1) * 8)));
      if (match) atomicAdd(&histw[hb + (int)((k >> (d * 8)) & 255u)], 1);
    }
    __syncthreads();
    if (tid < 256) {
      int ssum = 0;
#pragma unroll
      for (int w = 0; w < HG; ++w) ssum += histw[w * 256 + tid];
      sbuf[tid] = ssum;
    }
    __syncthreads();
    // parallel suffix-sum over 256 buckets: sbuf[t] = sum_{b>=t} hist[b]
    for (int off = 1; off < 256; off <<= 1) {
      int v = 0;
      if (tid < 256 && tid + off < 256) v = sbuf[tid + off];
      __syncthreads();
      if (tid < 256) sbuf[tid] += v;
      __syncthreads();
    }
    if (tid < 256) {
      int c = sbuf[tid];
      int cn = (tid < 255) ? sbuf[tid + 1] : 0;
      if (c >= remaining && cn < remaining) {  // unique crossing bucket
        sh_prefix = prefix | ((u32)tid << (d * 8));
        sh_need = remaining - cn;
      }
    }
    __syncthreads();
    prefix = sh_prefix;
    remaining = sh_need;
    __syncthreads();
  }
  const u32 T = prefix;
  const int needEq = remaining;  // #to take among key32==T (>=1)

  // collect key32==T group (tiny; exact fp64 tie-break)
#pragma unroll
  for (int i = 0; i < TCH; ++i) {
    int j = j0 + i;
    if (j < DFF && key[i] == T) {
      int p = atomicAdd(&gcount, 1);
      if (p < 256) { gidx[p] = j; gkey[p] = (u64)__double_as_longlong(scores[j]); }
    }
  }
  __syncthreads();
  int gc = gcount; if (gc > 256) gc = 256;

  // selection mask + block scan -> rank[]
  bool sel[TCH];
  int cntSel = 0;
#pragma unroll
  for (int i = 0; i < TCH; ++i) {
    int j = j0 + i;
    bool s = false;
    if (j < DFF) {
      if (key[i] > T) s = true;
      else if (key[i] == T) {
        u64 myk = (u64)__double_as_longlong(scores[j]);
        int r = 0;
        for (int e = 0; e < gc; ++e) {
          u64 ke = gkey[e];
          if (ke > myk || (ke == myk && gidx[e] < j)) r++;
        }
        s = (r < needEq);
      }
    }
    sel[i] = s;
    cntSel += s ? 1 : 0;
  }
  int incl = block_incl_scan(cntSel, tid, wsums);
  int running = incl - cntSel;
#pragma unroll
  for (int i = 0; i < TCH; ++i) {
    int j = j0 + i;
    if (j < DFF) {
      rank[j] = running;
      if (sel[i]) running++;
    }
  }
  if (tid == 0) rank[DFF] = TOPK;
}

// ---------------------------------------------------------------------------
// 3) compaction gather (8 rows/block): coalesced float4 reads, LDS compaction
//    at rank[c]-rank[c0], dense pair-packed u32 stores. Pad-zero fused into
//    the blockIdx.x==0 blocks.
// ---------------------------------------------------------------------------
__device__ __forceinline__ u16 f2bf_rne(float f) {
  unsigned u = __float_as_uint(f);
  unsigned r = (u + 0x7fffu + ((u >> 16) & 1u)) >> 16;
  return (u16)r;
}

#define GCW 1024
#define GNR 8

__global__ __launch_bounds__(256) void compact_gather_k(const float* __restrict__ src,
                                                        const int* __restrict__ rank,
                                                        u16* __restrict__ dst) {
  __shared__ u16 buf[GNR][GCW];
  __shared__ int sh_se[2];
  const int c0 = blockIdx.x * GCW;
  const int row0 = blockIdx.y * GNR;
  if (threadIdx.x == 0) {
    int cend = c0 + GCW; if (cend > DFF) cend = DFF;
    sh_se[0] = rank[c0];
    sh_se[1] = rank[cend];
  }
  // fused pad-zero: 13 pad cols x GNR rows = 104 stores by the x==0 blocks
  if (blockIdx.x == 0 && threadIdx.x < (KPAD - TOPK) * GNR) {
    int rr = threadIdx.x / (KPAD - TOPK);
    int k = threadIdx.x - rr * (KPAD - TOPK);
    dst[(size_t)(row0 + rr) * KPAD + TOPK + k] = 0;
  }
  __syncthreads();
  const int start = sh_se[0];
  const int total = sh_se[1] - start;

  const int c = c0 + threadIdx.x * 4;
  if (total > 0 && c < DFF) {
    int r0 = rank[c], r1 = rank[c + 1], r2 = rank[c + 2], r3 = rank[c + 3], r4 = rank[c + 4];
#pragma unroll
    for (int rr = 0; rr < GNR; ++rr) {
      float4 v = *(const float4*)(src + (size_t)(row0 + rr) * DFF + c);
      if (r1 > r0) buf[rr][r0 - start] = f2bf_rne(v.x);
      if (r2 > r1) buf[rr][r1 - start] = f2bf_rne(v.y);
      if (r3 > r2) buf[rr][r2 - start] = f2bf_rne(v.z);
      if (r4 > r3) buf[rr][r3 - start] = f2bf_rne(v.w);
    }
  }
  __syncthreads();
  if (total > 0) {
    const int odd = start & 1;
    const int np = (total - odd) >> 1;
#pragma unroll
    for (int rr = 0; rr < GNR; ++rr) {
      u16* d = dst + (size_t)(row0 + rr) * KPAD;
      if (odd && threadIdx.x == 0) d[start] = buf[rr][0];
      const u16* bb = &buf[rr][odd];
      u16* da = d + start + odd;  // 4B-aligned
      for (int t = threadIdx.x; t < np; t += 256) {
        u32 v = (u32)bb[2 * t] | ((u32)bb[2 * t + 1] << 16);
        *(u32*)(da + 2 * t) = v;
      }
      if (((total - odd) & 1) && threadIdx.x == 0) d[start + total - 1] = buf[rr][total - 1];
    }
  }
}

// ---------------------------------------------------------------------------
// 4) NT GEMM: C[M,N] f32 = A[M,K] bf16 · B[N,K] bf16^T  (unchanged, 134 us)
// ---------------------------------------------------------------------------
#define BM 128
#define BN 128
#define BK 64

__device__ __forceinline__ void async_load16(const void* g, void* l) {
  __builtin_amdgcn_global_load_lds(
      (const __attribute__((address_space(1))) void*)g,
      (__attribute__((address_space(3))) void*)l, 16, 0, 0);
}

__global__ __launch_bounds__(256) void gemm_bt_k(const u16* __restrict__ A,
                                                 const u16* __restrict__ B,
                                                 float* __restrict__ C,
                                                 int M, int N, int Kt) {
  __shared__ __align__(16) u16 As[BM * BK];
  __shared__ __align__(16) u16 Bs[BN * BK];
  const int tid = threadIdx.x;
  const int lane = tid & 63;
  const int wave = tid >> 6;
  const int bm = blockIdx.y * BM;
  const int bn = blockIdx.x * BN;
  const int wrow = (wave >> 1) * 64;
  const int wcol = (wave & 1) * 64;

  floatx4 acc[4][4];
#pragma unroll
  for (int i = 0; i < 4; ++i)
#pragma unroll
    for (int j = 0; j < 4; ++j)
      acc[i][j] = (floatx4){0.f, 0.f, 0.f, 0.f};

  const int srow = wave * 8 + (lane >> 3);
  const int scol = (lane & 7) * 8;
  const u16* gA = A + (size_t)(bm + srow) * Kt + scol;
  const u16* gB = B + (size_t)(bn + srow) * Kt + scol;
  u16* lA = As + wave * 8 * BK;  // wave-uniform LDS base
  u16* lB = Bs + wave * 8 * BK;

  const u16* aptr = As + (wrow + (lane & 15)) * BK + (lane >> 4) * 8;
  const u16* bptr = Bs + (wcol + (lane & 15)) * BK + (lane >> 4) * 8;

  for (int k0 = 0; k0 < Kt; k0 += BK) {
#pragma unroll
    for (int i = 0; i < 4; ++i) {
      async_load16(gA + k0 + (size_t)i * 32 * Kt, lA + i * 32 * BK);
      async_load16(gB + k0 + (size_t)i * 32 * Kt, lB + i * 32 * BK);
    }
    __syncthreads();
#pragma unroll
    for (int ks = 0; ks < BK; ks += 32) {
      short8 af[4], bf[4];
#pragma unroll
      for (int i = 0; i < 4; ++i) af[i] = *(const short8*)(aptr + i * 16 * BK + ks);
#pragma unroll
      for (int j = 0; j < 4; ++j) bf[j] = *(const short8*)(bptr + j * 16 * BK + ks);
#pragma unroll
      for (int i = 0; i < 4; ++i)
#pragma unroll
        for (int j = 0; j < 4; ++j)
          acc[i][j] = __builtin_amdgcn_mfma_f32_16x16x32_bf16(af[i], bf[j], acc[i][j], 0, 0, 0);
    }
    __syncthreads();
  }

  // C/D layout (verified m89/m91): col = lane&15, row = (lane>>4)*4 + reg
#pragma unroll
  for (int i = 0; i < 4; ++i) {
#pragma unroll
    for (int j = 0; j < 4; ++j) {
      int row = bm + wrow + i * 16 + (lane >> 4) * 4;
      int col = bn + wcol + j * 16 + (lane & 15);
      float* p = C + (size_t)row * N + col;
#pragma unroll
      for (int r = 0; r < 4; ++r) p[(size_t)r * N] = acc[i][j][r];
    }
  }
}

// ---------------------------------------------------------------------------
// launch
// ---------------------------------------------------------------------------
extern "C" void kernel_launch(void* const* d_in, const int* in_sizes, int n_in,
                              void* d_out, int out_size, void* d_ws, size_t ws_size,
                              hipStream_t stream) {
  const float* x = (const float*)d_in[0];  // [2048, 11008]
  const float* W = (const float*)d_in[1];  // [4096, 11008]
  float* out = (float*)d_out;              // [2048, 4096]
  char* ws = (char*)d_ws;

  // workspace layout (~56 MB)
  double* partials = (double*)ws;                      // 16*11008*8 = 1,409,024 B
  double* scores = (double*)(ws + 1409024);            // 11008*8    =    88,064 B
  int* rank = (int*)(ws + 1409024 + 88064);            // (11008+1)*4 =  44,036 B
  u16* Xg = (u16*)(ws + (size_t)2 * 1024 * 1024);      // 2048*4416*2 = 18,087,936 B
  u16* Wg = (u16*)(ws + (size_t)2 * 1024 * 1024 + (size_t)S_TOK * KPAD * 2);  // 4096*4416*2

  score_partial_k<<<dim3(DFF / 256, RSPLIT), 256, 0, stream>>>(x, partials);
  topk32_k<<<1, 1024, 0, stream>>>(partials, scores, rank);
  compact_gather_k<<<dim3(11, S_TOK / GNR), 256, 0, stream>>>(x, rank, Xg);
  compact_gather_k<<<dim3(11, DMODEL / GNR), 256, 0, stream>>>(W, rank, Wg);
  gemm_bt_k<<<dim3(DMODEL / BN, S_TOK / BM), 256, 0, stream>>>(Xg, Wg, out, S_TOK, DMODEL, KPAD);
}